// Round 6
// baseline (40046.417 us; speedup 1.0000x reference)
//
#include <hip/hip_runtime.h>

namespace {
constexpr int NN   = 50000;   // nodes
constexpr int NE   = 200000;  // edges
constexpr int EMB  = 128;
constexpr int TD   = 64;
constexpr int ND   = 192;     // EMB + TD
constexpr int HC   = 256;     // heads * channels
constexpr int D1   = 448;     // ND + HC
constexpr int OUTD = 64;
constexpr int CH   = 50000;   // edge chunk
constexpr int NCH  = NE / CH; // 4
}

// node features written into xin1 columns [HC, HC+ND)
__global__ void node_feat_k(const float* __restrict__ x, const float* __restrict__ nlu,
                            const float* __restrict__ tw, const float* __restrict__ tb,
                            float* __restrict__ xin1) {
  int idx = blockIdx.x * blockDim.x + threadIdx.x;
  if (idx >= NN * ND) return;
  int n = idx / ND, d = idx - n * ND;
  float v;
  if (d < EMB) v = x[(size_t)n * EMB + d];
  else         v = cosf(nlu[n] * tw[d - EMB] + tb[d - EMB]);
  xin1[(size_t)n * D1 + HC + d] = v;
}

__global__ void relt_k(const float* __restrict__ ets, const int* __restrict__ batch,
                       const int* __restrict__ src, const float* __restrict__ elu,
                       float* __restrict__ relt) {
  int e = blockIdx.x * blockDim.x + threadIdx.x;
  if (e >= NE) return;
  relt[e] = ets[batch[src[e]]] - elu[e];
}

// ---- generic f32 GEMM: C[gm*ldC + bn..] = A[gm*lda + k] @ W(K,Nout) + bias --
__global__ __launch_bounds__(256) void gemm_k(const float* __restrict__ A, int lda,
                                              int M, int K,
                                              const float* __restrict__ W, int Nout,
                                              const float* __restrict__ bias,
                                              float* __restrict__ Cout, int ldC) {
  __shared__ __align__(16) float As[16][68];  // 68 floats = 272 B = 17x16B (aligned f4 reads)
  __shared__ __align__(16) float Ws[16][64];
  const int bm = blockIdx.x * 64;
  const int bn = blockIdx.y * 64;
  const int tid = threadIdx.x;
  const int tx = tid & 15, ty = tid >> 4;
  float acc[4][4] = {};

  for (int k0 = 0; k0 < K; k0 += 16) {
#pragma unroll
    for (int j = 0; j < 4; ++j) {
      int lin = tid + j * 256;
      int m = lin >> 4, kk = lin & 15;
      int gm = bm + m;
      As[kk][m] = (gm < M) ? A[(size_t)gm * lda + k0 + kk] : 0.f;
      int nn = lin & 63, kk2 = lin >> 6;
      Ws[kk2][nn] = W[(size_t)(k0 + kk2) * Nout + bn + nn];
    }
    __syncthreads();
#pragma unroll
    for (int kk = 0; kk < 16; ++kk) {
      const float4 av = *(const float4*)&As[kk][ty * 4];
      const float4 bv = *(const float4*)&Ws[kk][tx * 4];
      const float a4[4] = {av.x, av.y, av.z, av.w};
      const float b4[4] = {bv.x, bv.y, bv.z, bv.w};
#pragma unroll
      for (int i = 0; i < 4; ++i)
#pragma unroll
        for (int j = 0; j < 4; ++j) acc[i][j] += a4[i] * b4[j];
    }
    __syncthreads();
  }

#pragma unroll
  for (int i = 0; i < 4; ++i) {
    int gm = bm + ty * 4 + i;
    if (gm >= M) continue;
#pragma unroll
    for (int j = 0; j < 4; ++j) {
      int gn = bn + tx * 4 + j;
      Cout[(size_t)gm * ldC + gn] = acc[i][j] + (bias ? bias[gn] : 0.f);
    }
  }
}

// ---- edge-projection GEMM: eproj_chunk = ea(on the fly) @ We, K=ND ---------
__global__ __launch_bounds__(256) void eproj_gemm_k(const float* __restrict__ eattr,
                                                    const float* __restrict__ relt,
                                                    const float* __restrict__ tw,
                                                    const float* __restrict__ tb,
                                                    int e0, int ecount,
                                                    const float* __restrict__ We,
                                                    float* __restrict__ Cout) {
  __shared__ __align__(16) float As[16][68];
  __shared__ __align__(16) float Ws[16][64];
  const int bm = blockIdx.x * 64;
  const int bn = blockIdx.y * 64;
  const int tid = threadIdx.x;
  const int tx = tid & 15, ty = tid >> 4;
  float acc[4][4] = {};

  for (int k0 = 0; k0 < ND; k0 += 16) {
#pragma unroll
    for (int j = 0; j < 4; ++j) {
      int lin = tid + j * 256;
      int m = lin >> 4, kk = lin & 15;
      int gm = bm + m;
      float a = 0.f;
      if (gm < ecount) {
        int ge = e0 + gm;
        int kg = k0 + kk;
        a = (kg < EMB) ? eattr[(size_t)ge * EMB + kg]
                       : cosf(relt[ge] * tw[kg - EMB] + tb[kg - EMB]);
      }
      As[kk][m] = a;
      int nn = lin & 63, kk2 = lin >> 6;
      Ws[kk2][nn] = We[(size_t)(k0 + kk2) * HC + bn + nn];
    }
    __syncthreads();
#pragma unroll
    for (int kk = 0; kk < 16; ++kk) {
      const float4 av = *(const float4*)&As[kk][ty * 4];
      const float4 bv = *(const float4*)&Ws[kk][tx * 4];
      const float a4[4] = {av.x, av.y, av.z, av.w};
      const float b4[4] = {bv.x, bv.y, bv.z, bv.w};
#pragma unroll
      for (int i = 0; i < 4; ++i)
#pragma unroll
        for (int j = 0; j < 4; ++j) acc[i][j] += a4[i] * b4[j];
    }
    __syncthreads();
  }

#pragma unroll
  for (int i = 0; i < 4; ++i) {
    int gm = bm + ty * 4 + i;
    if (gm >= ecount) continue;
#pragma unroll
    for (int j = 0; j < 4; ++j)
      Cout[(size_t)gm * HC + bn + tx * 4 + j] = acc[i][j];
  }
}

__global__ void init_k(float* __restrict__ svec, float* __restrict__ agg) {
  int idx = blockIdx.x * blockDim.x + threadIdx.x;
  if (idx < NN * 4)  svec[idx] = 0.f;
  if (idx < NN * HC) agg[idx] = 0.f;
}

// fused alpha+aggregate: one wave per edge (4 heads x 16 lanes x 4 ch).
// No max-subtraction: exp(alpha) is safe in f32 here (|alpha| ~ O(10)),
// and a = exp(a)/sum exp(a) is invariant to the shift.
__global__ void edge_pass_k(const float* __restrict__ q, const float* __restrict__ kmat,
                            const float* __restrict__ vmat, const float* __restrict__ ep,
                            int e0, int ecount,
                            const int* __restrict__ src, const int* __restrict__ tgt,
                            float* __restrict__ svec, float* __restrict__ agg) {
  int er = blockIdx.x * 4 + (threadIdx.x >> 6);
  if (er >= ecount) return;
  int e = e0 + er;
  int lane = threadIdx.x & 63;
  int h = lane >> 4;
  int c = (lane & 15) * 4;
  int sn = src[e], tn = tgt[e];
  const float4 qv = *(const float4*)&q[(size_t)tn * HC + h * 64 + c];
  const float4 kv = *(const float4*)&kmat[(size_t)sn * HC + h * 64 + c];
  const float4 ev = *(const float4*)&ep[(size_t)er * HC + h * 64 + c];
  float d = qv.x * (kv.x + ev.x) + qv.y * (kv.y + ev.y) +
            qv.z * (kv.z + ev.z) + qv.w * (kv.w + ev.w);
#pragma unroll
  for (int off = 8; off >= 1; off >>= 1) d += __shfl_xor(d, off, 64);
  float ex = expf(d * 0.125f);  // 1/sqrt(C)=1/8
  if ((lane & 15) == 0) atomicAdd(&svec[(size_t)tn * 4 + h], ex);
  const float4 vv = *(const float4*)&vmat[(size_t)sn * HC + h * 64 + c];
  float* dst = &agg[(size_t)tn * HC + h * 64 + c];
  atomicAdd(dst + 0, ex * (vv.x + ev.x));
  atomicAdd(dst + 1, ex * (vv.y + ev.y));
  atomicAdd(dst + 2, ex * (vv.z + ev.z));
  atomicAdd(dst + 3, ex * (vv.w + ev.w));
}

// xin1[:, 0:HC] currently holds skip; add normalized aggregate in place.
__global__ void finish0_k(const float* __restrict__ agg, const float* __restrict__ svec,
                          float* __restrict__ xin1) {
  int idx = blockIdx.x * blockDim.x + threadIdx.x;
  if (idx >= NN * HC) return;
  int n = idx >> 8, d = idx & 255;
  float s = svec[(size_t)n * 4 + (d >> 6)];
  xin1[(size_t)n * D1 + d] += agg[idx] / (s + 1e-16f);
}

// h1 (into qb) = agg/s + skip (in kb)
__global__ void finish1_k(const float* __restrict__ agg, const float* __restrict__ svec,
                          const float* __restrict__ skip, float* __restrict__ h1) {
  int idx = blockIdx.x * blockDim.x + threadIdx.x;
  if (idx >= NN * HC) return;
  int n = idx >> 8, d = idx & 255;
  float s = svec[(size_t)n * 4 + (d >> 6)];
  h1[idx] = agg[idx] / (s + 1e-16f) + skip[idx];
}

// ---- launch ---------------------------------------------------------------

extern "C" void kernel_launch(void* const* d_in, const int* in_sizes, int n_in,
                              void* d_out, int out_size, void* d_ws, size_t ws_size,
                              hipStream_t stream) {
  const float* ets   = (const float*)d_in[0];
  const float* x     = (const float*)d_in[1];
  const float* nlu   = (const float*)d_in[2];
  const float* eattr = (const float*)d_in[3];
  const float* elu   = (const float*)d_in[4];
  const int*   batch = (const int*)d_in[5];
  const int*   eidx  = (const int*)d_in[6];
  const float* tw    = (const float*)d_in[7];
  const float* tb    = (const float*)d_in[8];
  const float* Wq0 = (const float*)d_in[9];  const float* bq0 = (const float*)d_in[10];
  const float* Wk0 = (const float*)d_in[11]; const float* bk0 = (const float*)d_in[12];
  const float* Wv0 = (const float*)d_in[13]; const float* bv0 = (const float*)d_in[14];
  const float* We0 = (const float*)d_in[15];
  const float* Ws0 = (const float*)d_in[16]; const float* bs0 = (const float*)d_in[17];
  const float* Wq1 = (const float*)d_in[18]; const float* bq1 = (const float*)d_in[19];
  const float* Wk1 = (const float*)d_in[20]; const float* bk1 = (const float*)d_in[21];
  const float* Wv1 = (const float*)d_in[22]; const float* bv1 = (const float*)d_in[23];
  const float* We1 = (const float*)d_in[24];
  const float* Ws1 = (const float*)d_in[25]; const float* bs1 = (const float*)d_in[26];
  const float* linW = (const float*)d_in[27]; const float* linb = (const float*)d_in[28];

  const int* srcv = eidx;
  const int* tgtv = eidx + NE;

  // workspace: 347.2 MB total (was 748 MB -> suspected d_ws overflow / abort)
  float* ws = (float*)d_ws;
  size_t o = 0;
  float* relt   = ws + o; o += NE;                 //  0.8 MB
  float* eprojc = ws + o; o += (size_t)CH * HC;    // 51.2 MB (per-chunk)
  float* qb     = ws + o; o += (size_t)NN * HC;    // 51.2 MB
  float* kb     = ws + o; o += (size_t)NN * HC;    // 51.2 MB
  float* vb     = ws + o; o += (size_t)NN * HC;    // 51.2 MB
  float* svec   = ws + o; o += (size_t)NN * 4;     //  0.8 MB
  float* agg    = ws + o; o += (size_t)NN * HC;    // 51.2 MB
  float* xin1   = ws + o; o += (size_t)NN * D1;    // 89.6 MB

  dim3 blk(256);
  dim3 gn((NN + 63) / 64, HC / 64);
  dim3 gep((CH + 63) / 64, HC / 64);
  dim3 gf((NN + 63) / 64, 1);
  const int initg = (NN * HC + 255) / 256;
  const int epg   = (CH + 3) / 4;

  node_feat_k<<<(NN * ND + 255) / 256, blk, 0, stream>>>(x, nlu, tw, tb, xin1);
  relt_k<<<(NE + 255) / 256, blk, 0, stream>>>(ets, batch, srcv, elu, relt);

  // ---- layer 0 (A = xin1 cols [HC,HC+ND), lda=D1) ----
  gemm_k<<<gn, blk, 0, stream>>>(xin1 + HC, D1, NN, ND, Wq0, HC, bq0, qb, HC);
  gemm_k<<<gn, blk, 0, stream>>>(xin1 + HC, D1, NN, ND, Wk0, HC, bk0, kb, HC);
  gemm_k<<<gn, blk, 0, stream>>>(xin1 + HC, D1, NN, ND, Wv0, HC, bv0, vb, HC);
  // skip0 straight into xin1 cols [0,HC)  (disjoint from A columns)
  gemm_k<<<gn, blk, 0, stream>>>(xin1 + HC, D1, NN, ND, Ws0, HC, bs0, xin1, D1);
  init_k<<<initg, blk, 0, stream>>>(svec, agg);
  for (int ch = 0; ch < NCH; ++ch) {
    eproj_gemm_k<<<gep, blk, 0, stream>>>(eattr, relt, tw, tb, ch * CH, CH, We0, eprojc);
    edge_pass_k<<<epg, blk, 0, stream>>>(qb, kb, vb, eprojc, ch * CH, CH, srcv, tgtv, svec, agg);
  }
  finish0_k<<<initg, blk, 0, stream>>>(agg, svec, xin1);

  // ---- layer 1 (A = xin1, K=D1) ----
  gemm_k<<<gn, blk, 0, stream>>>(xin1, D1, NN, D1, Wq1, HC, bq1, qb, HC);
  gemm_k<<<gn, blk, 0, stream>>>(xin1, D1, NN, D1, Wk1, HC, bk1, kb, HC);
  gemm_k<<<gn, blk, 0, stream>>>(xin1, D1, NN, D1, Wv1, HC, bv1, vb, HC);
  init_k<<<initg, blk, 0, stream>>>(svec, agg);
  for (int ch = 0; ch < NCH; ++ch) {
    eproj_gemm_k<<<gep, blk, 0, stream>>>(eattr, relt, tw, tb, ch * CH, CH, We1, eprojc);
    edge_pass_k<<<epg, blk, 0, stream>>>(qb, kb, vb, eprojc, ch * CH, CH, srcv, tgtv, svec, agg);
  }
  // skip1 -> kb (free after the edge passes above; stream order guarantees this)
  gemm_k<<<gn, blk, 0, stream>>>(xin1, D1, NN, D1, Ws1, HC, bs1, kb, HC);
  finish1_k<<<initg, blk, 0, stream>>>(agg, svec, kb, qb);

  // ---- final linear: d_out = h1 @ linW + linb ----
  gemm_k<<<gf, blk, 0, stream>>>(qb, HC, NN, HC, linW, OUTD, linb, (float*)d_out, OUTD);
}

// Round 7
// 3610.604 us; speedup vs baseline: 11.0913x; 11.0913x over previous
//
#include <hip/hip_runtime.h>

namespace {
constexpr int NN   = 50000;   // nodes
constexpr int NE   = 200000;  // edges
constexpr int EMB  = 128;
constexpr int TD   = 64;
constexpr int ND   = 192;     // EMB + TD
constexpr int HC   = 256;     // heads * channels
constexpr int D1   = 448;     // ND + HC
constexpr int OUTD = 64;
constexpr int CH   = 50000;   // edge chunk
constexpr int NCH  = NE / CH; // 4
}

// node features written into xin1 columns [HC, HC+ND)
__global__ void node_feat_k(const float* __restrict__ x, const float* __restrict__ nlu,
                            const float* __restrict__ tw, const float* __restrict__ tb,
                            float* __restrict__ xin1) {
  int idx = blockIdx.x * blockDim.x + threadIdx.x;
  if (idx >= NN * ND) return;
  int n = idx / ND, d = idx - n * ND;
  float v;
  if (d < EMB) v = x[(size_t)n * EMB + d];
  else         v = cosf(nlu[n] * tw[d - EMB] + tb[d - EMB]);
  xin1[(size_t)n * D1 + HC + d] = v;
}

__global__ void relt_k(const float* __restrict__ ets, const int* __restrict__ batch,
                       const int* __restrict__ src, const float* __restrict__ elu,
                       float* __restrict__ relt) {
  int e = blockIdx.x * blockDim.x + threadIdx.x;
  if (e >= NE) return;
  relt[e] = ets[batch[src[e]]] - elu[e];
}

// chunk time-encoding table: teb[er][t] = cos(relt[e0+er]*tw[t]+tb[t])
// cosf lives ONLY in elementwise kernels: its ocml slow path maxed VGPRs (256)
// inside the GEMM staging loop and caused scratch-spill thrashing (7.4 GB
// fetch/dispatch, VALUBusy 1.4% -- round-6 profile).
__global__ void te_k(const float* __restrict__ relt, const float* __restrict__ tw,
                     const float* __restrict__ tb, int e0, float* __restrict__ teb) {
  int idx = blockIdx.x * blockDim.x + threadIdx.x;
  if (idx >= CH * TD) return;
  int er = idx >> 6, t = idx & 63;
  teb[idx] = cosf(relt[e0 + er] * tw[t] + tb[t]);
}

// ---- generic f32 GEMM: C[gm*ldC + bn..] = A[gm*lda + k] @ W(K,Nout) + bias --
__global__ __launch_bounds__(256) void gemm_k(const float* __restrict__ A, int lda,
                                              int M, int K,
                                              const float* __restrict__ W, int Nout,
                                              const float* __restrict__ bias,
                                              float* __restrict__ Cout, int ldC) {
  __shared__ __align__(16) float As[16][68];  // 68 floats = 272 B (16B-aligned f4 rows)
  __shared__ __align__(16) float Ws[16][64];
  const int bm = blockIdx.x * 64;
  const int bn = blockIdx.y * 64;
  const int tid = threadIdx.x;
  const int tx = tid & 15, ty = tid >> 4;
  float acc[4][4] = {};

  for (int k0 = 0; k0 < K; k0 += 16) {
#pragma unroll
    for (int j = 0; j < 4; ++j) {
      int lin = tid + j * 256;
      int m = lin >> 4, kk = lin & 15;
      int gm = bm + m;
      As[kk][m] = (gm < M) ? A[(size_t)gm * lda + k0 + kk] : 0.f;
      int nn = lin & 63, kk2 = lin >> 6;
      Ws[kk2][nn] = W[(size_t)(k0 + kk2) * Nout + bn + nn];
    }
    __syncthreads();
#pragma unroll
    for (int kk = 0; kk < 16; ++kk) {
      const float4 av = *(const float4*)&As[kk][ty * 4];
      const float4 bv = *(const float4*)&Ws[kk][tx * 4];
      const float a4[4] = {av.x, av.y, av.z, av.w};
      const float b4[4] = {bv.x, bv.y, bv.z, bv.w};
#pragma unroll
      for (int i = 0; i < 4; ++i)
#pragma unroll
        for (int j = 0; j < 4; ++j) acc[i][j] += a4[i] * b4[j];
    }
    __syncthreads();
  }

#pragma unroll
  for (int i = 0; i < 4; ++i) {
    int gm = bm + ty * 4 + i;
    if (gm >= M) continue;
#pragma unroll
    for (int j = 0; j < 4; ++j) {
      int gn = bn + tx * 4 + j;
      Cout[(size_t)gm * ldC + gn] = acc[i][j] + (bias ? bias[gn] : 0.f);
    }
  }
}

// ---- edge-projection GEMM: A row ge = [eattr[ge] | teb[ge-e0]], K=ND -------
__global__ __launch_bounds__(256) void eproj_gemm_k(const float* __restrict__ eattr,
                                                    const float* __restrict__ teb,
                                                    int e0, int ecount,
                                                    const float* __restrict__ We,
                                                    float* __restrict__ Cout) {
  __shared__ __align__(16) float As[16][68];
  __shared__ __align__(16) float Ws[16][64];
  const int bm = blockIdx.x * 64;
  const int bn = blockIdx.y * 64;
  const int tid = threadIdx.x;
  const int tx = tid & 15, ty = tid >> 4;
  float acc[4][4] = {};

  for (int k0 = 0; k0 < ND; k0 += 16) {
#pragma unroll
    for (int j = 0; j < 4; ++j) {
      int lin = tid + j * 256;
      int m = lin >> 4, kk = lin & 15;
      int gm = bm + m;   // chunk-local row
      float a = 0.f;
      if (gm < ecount) {
        int kg = k0 + kk;
        a = (kg < EMB) ? eattr[(size_t)(e0 + gm) * EMB + kg]
                       : teb[(size_t)gm * TD + (kg - EMB)];
      }
      As[kk][m] = a;
      int nn = lin & 63, kk2 = lin >> 6;
      Ws[kk2][nn] = We[(size_t)(k0 + kk2) * HC + bn + nn];
    }
    __syncthreads();
#pragma unroll
    for (int kk = 0; kk < 16; ++kk) {
      const float4 av = *(const float4*)&As[kk][ty * 4];
      const float4 bv = *(const float4*)&Ws[kk][tx * 4];
      const float a4[4] = {av.x, av.y, av.z, av.w};
      const float b4[4] = {bv.x, bv.y, bv.z, bv.w};
#pragma unroll
      for (int i = 0; i < 4; ++i)
#pragma unroll
        for (int j = 0; j < 4; ++j) acc[i][j] += a4[i] * b4[j];
    }
    __syncthreads();
  }

#pragma unroll
  for (int i = 0; i < 4; ++i) {
    int gm = bm + ty * 4 + i;
    if (gm >= ecount) continue;
#pragma unroll
    for (int j = 0; j < 4; ++j)
      Cout[(size_t)gm * HC + bn + tx * 4 + j] = acc[i][j];
  }
}

__global__ void init_k(float* __restrict__ svec, float* __restrict__ agg) {
  int idx = blockIdx.x * blockDim.x + threadIdx.x;
  if (idx < NN * 4)  svec[idx] = 0.f;
  if (idx < NN * HC) agg[idx] = 0.f;
}

// fused alpha+aggregate: one wave per edge (4 heads x 16 lanes x 4 ch).
// No max-subtraction: exp(alpha) safe in f32 here; softmax shift-invariant.
__global__ void edge_pass_k(const float* __restrict__ q, const float* __restrict__ kmat,
                            const float* __restrict__ vmat, const float* __restrict__ ep,
                            int e0, int ecount,
                            const int* __restrict__ src, const int* __restrict__ tgt,
                            float* __restrict__ svec, float* __restrict__ agg) {
  int er = blockIdx.x * 4 + (threadIdx.x >> 6);
  if (er >= ecount) return;
  int e = e0 + er;
  int lane = threadIdx.x & 63;
  int h = lane >> 4;
  int c = (lane & 15) * 4;
  int sn = src[e], tn = tgt[e];
  const float4 qv = *(const float4*)&q[(size_t)tn * HC + h * 64 + c];
  const float4 kv = *(const float4*)&kmat[(size_t)sn * HC + h * 64 + c];
  const float4 ev = *(const float4*)&ep[(size_t)er * HC + h * 64 + c];
  float d = qv.x * (kv.x + ev.x) + qv.y * (kv.y + ev.y) +
            qv.z * (kv.z + ev.z) + qv.w * (kv.w + ev.w);
#pragma unroll
  for (int off = 8; off >= 1; off >>= 1) d += __shfl_xor(d, off, 64);
  float ex = expf(d * 0.125f);  // 1/sqrt(C)=1/8
  if ((lane & 15) == 0) atomicAdd(&svec[(size_t)tn * 4 + h], ex);
  const float4 vv = *(const float4*)&vmat[(size_t)sn * HC + h * 64 + c];
  float* dst = &agg[(size_t)tn * HC + h * 64 + c];
  atomicAdd(dst + 0, ex * (vv.x + ev.x));
  atomicAdd(dst + 1, ex * (vv.y + ev.y));
  atomicAdd(dst + 2, ex * (vv.z + ev.z));
  atomicAdd(dst + 3, ex * (vv.w + ev.w));
}

// xin1[:, 0:HC] currently holds skip; add normalized aggregate in place.
__global__ void finish0_k(const float* __restrict__ agg, const float* __restrict__ svec,
                          float* __restrict__ xin1) {
  int idx = blockIdx.x * blockDim.x + threadIdx.x;
  if (idx >= NN * HC) return;
  int n = idx >> 8, d = idx & 255;
  float s = svec[(size_t)n * 4 + (d >> 6)];
  xin1[(size_t)n * D1 + d] += agg[idx] / (s + 1e-16f);
}

// h1 (into qb) = agg/s + skip (in kb)
__global__ void finish1_k(const float* __restrict__ agg, const float* __restrict__ svec,
                          const float* __restrict__ skip, float* __restrict__ h1) {
  int idx = blockIdx.x * blockDim.x + threadIdx.x;
  if (idx >= NN * HC) return;
  int n = idx >> 8, d = idx & 255;
  float s = svec[(size_t)n * 4 + (d >> 6)];
  h1[idx] = agg[idx] / (s + 1e-16f) + skip[idx];
}

// ---- launch ---------------------------------------------------------------

extern "C" void kernel_launch(void* const* d_in, const int* in_sizes, int n_in,
                              void* d_out, int out_size, void* d_ws, size_t ws_size,
                              hipStream_t stream) {
  const float* ets   = (const float*)d_in[0];
  const float* x     = (const float*)d_in[1];
  const float* nlu   = (const float*)d_in[2];
  const float* eattr = (const float*)d_in[3];
  const float* elu   = (const float*)d_in[4];
  const int*   batch = (const int*)d_in[5];
  const int*   eidx  = (const int*)d_in[6];
  const float* tw    = (const float*)d_in[7];
  const float* tb    = (const float*)d_in[8];
  const float* Wq0 = (const float*)d_in[9];  const float* bq0 = (const float*)d_in[10];
  const float* Wk0 = (const float*)d_in[11]; const float* bk0 = (const float*)d_in[12];
  const float* Wv0 = (const float*)d_in[13]; const float* bv0 = (const float*)d_in[14];
  const float* We0 = (const float*)d_in[15];
  const float* Ws0 = (const float*)d_in[16]; const float* bs0 = (const float*)d_in[17];
  const float* Wq1 = (const float*)d_in[18]; const float* bq1 = (const float*)d_in[19];
  const float* Wk1 = (const float*)d_in[20]; const float* bk1 = (const float*)d_in[21];
  const float* Wv1 = (const float*)d_in[22]; const float* bv1 = (const float*)d_in[23];
  const float* We1 = (const float*)d_in[24];
  const float* Ws1 = (const float*)d_in[25]; const float* bs1 = (const float*)d_in[26];
  const float* linW = (const float*)d_in[27]; const float* linb = (const float*)d_in[28];

  const int* srcv = eidx;
  const int* tgtv = eidx + NE;

  // workspace: 360.0 MB total (347.2 proven-good + 12.8 te chunk table)
  float* ws = (float*)d_ws;
  size_t o = 0;
  float* relt   = ws + o; o += NE;                 //  0.8 MB
  float* eprojc = ws + o; o += (size_t)CH * HC;    // 51.2 MB (per-chunk)
  float* teb    = ws + o; o += (size_t)CH * TD;    // 12.8 MB (per-chunk)
  float* qb     = ws + o; o += (size_t)NN * HC;    // 51.2 MB
  float* kb     = ws + o; o += (size_t)NN * HC;    // 51.2 MB
  float* vb     = ws + o; o += (size_t)NN * HC;    // 51.2 MB
  float* svec   = ws + o; o += (size_t)NN * 4;     //  0.8 MB
  float* agg    = ws + o; o += (size_t)NN * HC;    // 51.2 MB
  float* xin1   = ws + o; o += (size_t)NN * D1;    // 89.6 MB

  dim3 blk(256);
  dim3 gn((NN + 63) / 64, HC / 64);
  dim3 gep((CH + 63) / 64, HC / 64);
  dim3 gf((NN + 63) / 64, 1);
  const int initg = (NN * HC + 255) / 256;
  const int epg   = (CH + 3) / 4;
  const int teg   = (CH * TD + 255) / 256;

  node_feat_k<<<(NN * ND + 255) / 256, blk, 0, stream>>>(x, nlu, tw, tb, xin1);
  relt_k<<<(NE + 255) / 256, blk, 0, stream>>>(ets, batch, srcv, elu, relt);

  // ---- layer 0 (A = xin1 cols [HC,HC+ND), lda=D1) ----
  gemm_k<<<gn, blk, 0, stream>>>(xin1 + HC, D1, NN, ND, Wq0, HC, bq0, qb, HC);
  gemm_k<<<gn, blk, 0, stream>>>(xin1 + HC, D1, NN, ND, Wk0, HC, bk0, kb, HC);
  gemm_k<<<gn, blk, 0, stream>>>(xin1 + HC, D1, NN, ND, Wv0, HC, bv0, vb, HC);
  // skip0 straight into xin1 cols [0,HC)  (disjoint from A columns)
  gemm_k<<<gn, blk, 0, stream>>>(xin1 + HC, D1, NN, ND, Ws0, HC, bs0, xin1, D1);
  init_k<<<initg, blk, 0, stream>>>(svec, agg);
  for (int ch = 0; ch < NCH; ++ch) {
    te_k<<<teg, blk, 0, stream>>>(relt, tw, tb, ch * CH, teb);
    eproj_gemm_k<<<gep, blk, 0, stream>>>(eattr, teb, ch * CH, CH, We0, eprojc);
    edge_pass_k<<<epg, blk, 0, stream>>>(qb, kb, vb, eprojc, ch * CH, CH, srcv, tgtv, svec, agg);
  }
  finish0_k<<<initg, blk, 0, stream>>>(agg, svec, xin1);

  // ---- layer 1 (A = xin1, K=D1) ----
  gemm_k<<<gn, blk, 0, stream>>>(xin1, D1, NN, D1, Wq1, HC, bq1, qb, HC);
  gemm_k<<<gn, blk, 0, stream>>>(xin1, D1, NN, D1, Wk1, HC, bk1, kb, HC);
  gemm_k<<<gn, blk, 0, stream>>>(xin1, D1, NN, D1, Wv1, HC, bv1, vb, HC);
  init_k<<<initg, blk, 0, stream>>>(svec, agg);
  for (int ch = 0; ch < NCH; ++ch) {
    te_k<<<teg, blk, 0, stream>>>(relt, tw, tb, ch * CH, teb);
    eproj_gemm_k<<<gep, blk, 0, stream>>>(eattr, teb, ch * CH, CH, We1, eprojc);
    edge_pass_k<<<epg, blk, 0, stream>>>(qb, kb, vb, eprojc, ch * CH, CH, srcv, tgtv, svec, agg);
  }
  // skip1 -> kb (free after the edge passes above; stream order guarantees this)
  gemm_k<<<gn, blk, 0, stream>>>(xin1, D1, NN, D1, Ws1, HC, bs1, kb, HC);
  finish1_k<<<initg, blk, 0, stream>>>(agg, svec, kb, qb);

  // ---- final linear: d_out = h1 @ linW + linb ----
  gemm_k<<<gf, blk, 0, stream>>>(qb, HC, NN, HC, linW, OUTD, linb, (float*)d_out, OUTD);
}

// Round 10
// 2630.419 us; speedup vs baseline: 15.2244x; 1.3726x over previous
//
#include <hip/hip_runtime.h>

namespace {
constexpr int NN   = 50000;   // nodes
constexpr int NE   = 200000;  // edges
constexpr int EMB  = 128;
constexpr int TD   = 64;
constexpr int ND   = 192;     // EMB + TD
constexpr int HC   = 256;     // heads * channels
constexpr int D1   = 448;     // ND + HC
constexpr int OUTD = 64;
constexpr int CH   = 25000;   // edge chunk
constexpr int NCH  = NE / CH; // 8
}

typedef short  bf16x8 __attribute__((ext_vector_type(8)));
typedef float  f32x4  __attribute__((ext_vector_type(4)));

__device__ __forceinline__ unsigned short f2bf(float f) {
  union { float f; unsigned u; } v; v.f = f;
  unsigned r = v.u + 0x7fffu + ((v.u >> 16) & 1u);  // RNE
  return (unsigned short)(r >> 16);
}

// ---- feature construction -------------------------------------------------

// node features -> xin1_bf cols [HC, HC+ND), bf16
__global__ void node_feat_k(const float* __restrict__ x, const float* __restrict__ nlu,
                            const float* __restrict__ tw, const float* __restrict__ tb,
                            unsigned short* __restrict__ xin1) {
  int idx = blockIdx.x * blockDim.x + threadIdx.x;
  if (idx >= NN * ND) return;
  int n = idx / ND, d = idx - n * ND;
  float v;
  if (d < EMB) v = x[(size_t)n * EMB + d];
  else         v = cosf(nlu[n] * tw[d - EMB] + tb[d - EMB]);
  xin1[(size_t)n * D1 + HC + d] = f2bf(v);
}

__global__ void relt_k(const float* __restrict__ ets, const int* __restrict__ batch,
                       const int* __restrict__ src, const float* __restrict__ elu,
                       float* __restrict__ relt) {
  int e = blockIdx.x * blockDim.x + threadIdx.x;
  if (e >= NE) return;
  relt[e] = ets[batch[src[e]]] - elu[e];
}

// per-chunk edge features [eattr | cos(te)] -> bf16 (cosf only in elementwise)
__global__ void eabf_k(const float* __restrict__ eattr, const float* __restrict__ relt,
                       const float* __restrict__ tw, const float* __restrict__ tb,
                       int e0, unsigned short* __restrict__ eabf) {
  int idx = blockIdx.x * blockDim.x + threadIdx.x;
  if (idx >= CH * ND) return;
  int er = idx / ND, d = idx - er * ND;
  float v;
  if (d < EMB) v = eattr[(size_t)(e0 + er) * EMB + d];
  else         v = cosf(relt[e0 + er] * tw[d - EMB] + tb[d - EMB]);
  eabf[idx] = f2bf(v);
}

// ---- weight packing -------------------------------------------------------
// Wt[n][k] = W_sel[k][n&255] (bf16, transposed, q|k|v|s concatenated); bc[n]
__global__ void packw_k(const float* __restrict__ Wq, const float* __restrict__ Wk,
                        const float* __restrict__ Wv, const float* __restrict__ Ws,
                        const float* __restrict__ bq, const float* __restrict__ bk,
                        const float* __restrict__ bv, const float* __restrict__ bs,
                        int K, unsigned short* __restrict__ Wt, float* __restrict__ bc) {
  int idx = blockIdx.x * blockDim.x + threadIdx.x;
  if (idx < 1024 * K) {
    int n = idx / K, k = idx - n * K;
    int sel = n >> 8, col = n & 255;
    const float* W = sel == 0 ? Wq : sel == 1 ? Wk : sel == 2 ? Wv : Ws;
    Wt[idx] = f2bf(W[(size_t)k * 256 + col]);
  }
  if (idx < 1024) {
    int sel = idx >> 8, col = idx & 255;
    const float* b = sel == 0 ? bq : sel == 1 ? bk : sel == 2 ? bv : bs;
    bc[idx] = b[col];
  }
}

__global__ void packwe_k(const float* __restrict__ We, unsigned short* __restrict__ Wt) {
  int idx = blockIdx.x * blockDim.x + threadIdx.x;
  if (idx >= 256 * ND) return;
  int n = idx / ND, k = idx - n * ND;
  Wt[idx] = f2bf(We[(size_t)k * 256 + n]);
}

// ---- bf16 MFMA GEMM ------------------------------------------------------
// C = A(bf16, M x K, row-major lda) @ Bt^T (Bt bf16 [Ntot][K] row-major) + bias
// 64x64 tile, 4 waves in 2x2, each wave 32x32 via 2x2 mfma_f32_16x16x32_bf16.
// A/B staged as [kgroup][row][8k] with IDENTICAL k->slot packing for both
// operands => correctness independent of the HW k-map (A/B layouts share it).
// Output buffer selected by bn>>8 (q|k|v|skip fusion); ldC fixed 256.
__global__ __launch_bounds__(256) void mfma_gemm_k(
    const unsigned short* __restrict__ A, int lda, int M, int K,
    const unsigned short* __restrict__ Bt, const float* __restrict__ bias,
    float* __restrict__ o0, float* __restrict__ o1,
    float* __restrict__ o2, float* __restrict__ o3) {
  __shared__ short Asm[4 * 64 * 8];
  __shared__ short Bsm[4 * 64 * 8];
  const int bm = blockIdx.x * 64;
  const int bn = blockIdx.y * 64;
  const int tid = threadIdx.x;
  const int kg = tid >> 6;          // wave id == k-group staged
  const int r  = tid & 63;          // row (m or n) staged
  const int lane = tid & 63;
  const int wm = ((tid >> 6) >> 1) * 32;   // wave's m-offset
  const int wn = ((tid >> 6) & 1) * 32;    // wave's n-offset
  const int l15 = lane & 15, lhi = lane >> 4;

  f32x4 acc[2][2] = {};

  bf16x8* As8 = (bf16x8*)Asm;
  bf16x8* Bs8 = (bf16x8*)Bsm;

  for (int k0 = 0; k0 < K; k0 += 32) {
    // stage: each wave writes one contiguous 1024B kg-block (conflict-free)
    bf16x8 av = {};
    int gm = bm + r;
    if (gm < M) av = *(const bf16x8*)&A[(size_t)gm * lda + k0 + kg * 8];
    As8[kg * 64 + r] = av;
    Bs8[kg * 64 + r] = *(const bf16x8*)&Bt[(size_t)(bn + r) * K + k0 + kg * 8];
    __syncthreads();

    bf16x8 a0 = As8[lhi * 64 + wm + l15];
    bf16x8 a1 = As8[lhi * 64 + wm + 16 + l15];
    bf16x8 b0 = Bs8[lhi * 64 + wn + l15];
    bf16x8 b1 = Bs8[lhi * 64 + wn + 16 + l15];
    acc[0][0] = __builtin_amdgcn_mfma_f32_16x16x32_bf16(a0, b0, acc[0][0], 0, 0, 0);
    acc[0][1] = __builtin_amdgcn_mfma_f32_16x16x32_bf16(a0, b1, acc[0][1], 0, 0, 0);
    acc[1][0] = __builtin_amdgcn_mfma_f32_16x16x32_bf16(a1, b0, acc[1][0], 0, 0, 0);
    acc[1][1] = __builtin_amdgcn_mfma_f32_16x16x32_bf16(a1, b1, acc[1][1], 0, 0, 0);
    __syncthreads();
  }

  const int bsel = bn >> 8;
  const int cb   = bn & 255;
  float* C = bsel == 0 ? o0 : bsel == 1 ? o1 : bsel == 2 ? o2 : o3;
#pragma unroll
  for (int mr = 0; mr < 2; ++mr)
#pragma unroll
    for (int nr = 0; nr < 2; ++nr) {
      int gcl = wn + nr * 16 + l15;               // 0..63 within tile
      float bval = bias ? bias[bn + gcl] : 0.f;
#pragma unroll
      for (int ri = 0; ri < 4; ++ri) {
        int row = bm + wm + mr * 16 + lhi * 4 + ri;   // C/D map (m89)
        if (row < M) C[(size_t)row * 256 + cb + gcl] = acc[mr][nr][ri] + bval;
      }
    }
}

// ---- f32 GEMM (kept for the small final linear) ---------------------------
__global__ __launch_bounds__(256) void gemm_k(const float* __restrict__ A, int lda,
                                              int M, int K,
                                              const float* __restrict__ W, int Nout,
                                              const float* __restrict__ bias,
                                              float* __restrict__ Cout, int ldC) {
  __shared__ __align__(16) float As[16][68];
  __shared__ __align__(16) float Ws[16][64];
  const int bm = blockIdx.x * 64;
  const int bn = blockIdx.y * 64;
  const int tid = threadIdx.x;
  const int tx = tid & 15, ty = tid >> 4;
  float acc[4][4] = {};

  for (int k0 = 0; k0 < K; k0 += 16) {
#pragma unroll
    for (int j = 0; j < 4; ++j) {
      int lin = tid + j * 256;
      int m = lin >> 4, kk = lin & 15;
      int gm = bm + m;
      As[kk][m] = (gm < M) ? A[(size_t)gm * lda + k0 + kk] : 0.f;
      int nn = lin & 63, kk2 = lin >> 6;
      Ws[kk2][nn] = W[(size_t)(k0 + kk2) * Nout + bn + nn];
    }
    __syncthreads();
#pragma unroll
    for (int kk = 0; kk < 16; ++kk) {
      const float4 av = *(const float4*)&As[kk][ty * 4];
      const float4 bv = *(const float4*)&Ws[kk][tx * 4];
      const float a4[4] = {av.x, av.y, av.z, av.w};
      const float b4[4] = {bv.x, bv.y, bv.z, bv.w};
#pragma unroll
      for (int i = 0; i < 4; ++i)
#pragma unroll
        for (int j = 0; j < 4; ++j) acc[i][j] += a4[i] * b4[j];
    }
    __syncthreads();
  }

#pragma unroll
  for (int i = 0; i < 4; ++i) {
    int gm = bm + ty * 4 + i;
    if (gm >= M) continue;
#pragma unroll
    for (int j = 0; j < 4; ++j) {
      int gn = bn + tx * 4 + j;
      Cout[(size_t)gm * ldC + gn] = acc[i][j] + (bias ? bias[gn] : 0.f);
    }
  }
}

// ---- attention ------------------------------------------------------------

__global__ void init_k(float* __restrict__ svec, float* __restrict__ agg) {
  int idx = blockIdx.x * blockDim.x + threadIdx.x;
  if (idx < NN * 4)  svec[idx] = 0.f;
  if (idx < NN * HC) agg[idx] = 0.f;
}

// fused alpha+aggregate: one wave per edge (4 heads x 16 lanes x 4 ch).
// No max-subtraction: softmax is shift-invariant; exp(alpha) safe in f32 here.
__global__ void edge_pass_k(const float* __restrict__ q, const float* __restrict__ kmat,
                            const float* __restrict__ vmat, const float* __restrict__ ep,
                            int e0, int ecount,
                            const int* __restrict__ src, const int* __restrict__ tgt,
                            float* __restrict__ svec, float* __restrict__ agg) {
  int er = blockIdx.x * 4 + (threadIdx.x >> 6);
  if (er >= ecount) return;
  int e = e0 + er;
  int lane = threadIdx.x & 63;
  int h = lane >> 4;
  int c = (lane & 15) * 4;
  int sn = src[e], tn = tgt[e];
  const float4 qv = *(const float4*)&q[(size_t)tn * HC + h * 64 + c];
  const float4 kv = *(const float4*)&kmat[(size_t)sn * HC + h * 64 + c];
  const float4 ev = *(const float4*)&ep[(size_t)er * HC + h * 64 + c];
  float d = qv.x * (kv.x + ev.x) + qv.y * (kv.y + ev.y) +
            qv.z * (kv.z + ev.z) + qv.w * (kv.w + ev.w);
#pragma unroll
  for (int off = 8; off >= 1; off >>= 1) d += __shfl_xor(d, off, 64);
  float ex = expf(d * 0.125f);  // 1/sqrt(C)=1/8
  if ((lane & 15) == 0) atomicAdd(&svec[(size_t)tn * 4 + h], ex);
  const float4 vv = *(const float4*)&vmat[(size_t)sn * HC + h * 64 + c];
  float* dst = &agg[(size_t)tn * HC + h * 64 + c];
  atomicAdd(dst + 0, ex * (vv.x + ev.x));
  atomicAdd(dst + 1, ex * (vv.y + ev.y));
  atomicAdd(dst + 2, ex * (vv.z + ev.z));
  atomicAdd(dst + 3, ex * (vv.w + ev.w));
}

// h0 = agg/s + skip -> bf16 into xin1 cols [0,HC)
__global__ void finish0_k(const float* __restrict__ agg, const float* __restrict__ svec,
                          const float* __restrict__ skip, unsigned short* __restrict__ xin1) {
  int idx = blockIdx.x * blockDim.x + threadIdx.x;
  if (idx >= NN * HC) return;
  int n = idx >> 8, d = idx & 255;
  float s = svec[(size_t)n * 4 + (d >> 6)];
  xin1[(size_t)n * D1 + d] = f2bf(agg[idx] / (s + 1e-16f) + skip[idx]);
}

// h1 = agg/s + skip (f32, feeds final f32 GEMM)
__global__ void finish1_k(const float* __restrict__ agg, const float* __restrict__ svec,
                          const float* __restrict__ skip, float* __restrict__ h1) {
  int idx = blockIdx.x * blockDim.x + threadIdx.x;
  if (idx >= NN * HC) return;
  int n = idx >> 8, d = idx & 255;
  float s = svec[(size_t)n * 4 + (d >> 6)];
  h1[idx] = agg[idx] / (s + 1e-16f) + skip[idx];
}

// ---- launch ---------------------------------------------------------------

extern "C" void kernel_launch(void* const* d_in, const int* in_sizes, int n_in,
                              void* d_out, int out_size, void* d_ws, size_t ws_size,
                              hipStream_t stream) {
  const float* ets   = (const float*)d_in[0];
  const float* x     = (const float*)d_in[1];
  const float* nlu   = (const float*)d_in[2];
  const float* eattr = (const float*)d_in[3];
  const float* elu   = (const float*)d_in[4];
  const int*   batch = (const int*)d_in[5];
  const int*   eidx  = (const int*)d_in[6];
  const float* tw    = (const float*)d_in[7];
  const float* tb    = (const float*)d_in[8];
  const float* Wq0 = (const float*)d_in[9];  const float* bq0 = (const float*)d_in[10];
  const float* Wk0 = (const float*)d_in[11]; const float* bk0 = (const float*)d_in[12];
  const float* Wv0 = (const float*)d_in[13]; const float* bv0 = (const float*)d_in[14];
  const float* We0 = (const float*)d_in[15];
  const float* Ws0 = (const float*)d_in[16]; const float* bs0 = (const float*)d_in[17];
  const float* Wq1 = (const float*)d_in[18]; const float* bq1 = (const float*)d_in[19];
  const float* Wk1 = (const float*)d_in[20]; const float* bk1 = (const float*)d_in[21];
  const float* Wv1 = (const float*)d_in[22]; const float* bv1 = (const float*)d_in[23];
  const float* We1 = (const float*)d_in[24];
  const float* Ws1 = (const float*)d_in[25]; const float* bs1 = (const float*)d_in[26];
  const float* linW = (const float*)d_in[27]; const float* linb = (const float*)d_in[28];

  const int* srcv = eidx;
  const int* tgtv = eidx + NE;

  // workspace: ~339 MB (proven-safe budget was 360 MB)
  float* ws = (float*)d_ws;
  size_t o = 0;
  float* relt   = ws + o; o += NE;                       //  0.8 MB
  unsigned short* eabf = (unsigned short*)(ws + o); o += (size_t)CH * ND / 2;   //  9.6 MB
  float* eprojc = ws + o; o += (size_t)CH * HC;          // 25.6 MB
  float* qb     = ws + o; o += (size_t)NN * HC;          // 51.2 MB
  float* kb     = ws + o; o += (size_t)NN * HC;          // 51.2 MB
  float* vb     = ws + o; o += (size_t)NN * HC;          // 51.2 MB
  float* skipb  = ws + o; o += (size_t)NN * HC;          // 51.2 MB
  float* svec   = ws + o; o += (size_t)NN * 4;           //  0.8 MB
  float* agg    = ws + o; o += (size_t)NN * HC;          // 51.2 MB
  unsigned short* xin1 = (unsigned short*)(ws + o); o += (size_t)NN * D1 / 2;   // 44.8 MB
  unsigned short* Wc0t = (unsigned short*)(ws + o); o += 1024 * ND / 2;
  unsigned short* Wc1t = (unsigned short*)(ws + o); o += 1024 * D1 / 2;
  unsigned short* We0t = (unsigned short*)(ws + o); o += 256 * ND / 2;
  unsigned short* We1t = (unsigned short*)(ws + o); o += 256 * ND / 2;
  float* bc0    = ws + o; o += 1024;
  float* bc1    = ws + o; o += 1024;

  dim3 blk(256);
  dim3 gqkvs((NN + 63) / 64, 16);
  dim3 gep((CH + 63) / 64, 4);
  dim3 gf((NN + 63) / 64, 1);
  const int initg = (NN * HC + 255) / 256;
  const int epg   = (CH + 3) / 4;

  // features + weight packing
  node_feat_k<<<(NN * ND + 255) / 256, blk, 0, stream>>>(x, nlu, tw, tb, xin1);
  relt_k<<<(NE + 255) / 256, blk, 0, stream>>>(ets, batch, srcv, elu, relt);
  packw_k<<<(1024 * ND + 255) / 256, blk, 0, stream>>>(Wq0, Wk0, Wv0, Ws0, bq0, bk0, bv0, bs0, ND, Wc0t, bc0);
  packw_k<<<(1024 * D1 + 255) / 256, blk, 0, stream>>>(Wq1, Wk1, Wv1, Ws1, bq1, bk1, bv1, bs1, D1, Wc1t, bc1);
  packwe_k<<<(256 * ND + 255) / 256, blk, 0, stream>>>(We0, We0t);
  packwe_k<<<(256 * ND + 255) / 256, blk, 0, stream>>>(We1, We1t);

  // ---- layer 0: fused QKVS (A = xin1 cols [HC,448), K=192) ----
  mfma_gemm_k<<<gqkvs, blk, 0, stream>>>(xin1 + HC, D1, NN, ND, Wc0t, bc0, qb, kb, vb, skipb);
  init_k<<<initg, blk, 0, stream>>>(svec, agg);
  for (int ch = 0; ch < NCH; ++ch) {
    eabf_k<<<(CH * ND + 255) / 256, blk, 0, stream>>>(eattr, relt, tw, tb, ch * CH, eabf);
    mfma_gemm_k<<<gep, blk, 0, stream>>>(eabf, ND, CH, ND, We0t, nullptr, eprojc, eprojc, eprojc, eprojc);
    edge_pass_k<<<epg, blk, 0, stream>>>(qb, kb, vb, eprojc, ch * CH, CH, srcv, tgtv, svec, agg);
  }
  finish0_k<<<initg, blk, 0, stream>>>(agg, svec, skipb, xin1);

  // ---- layer 1: fused QKVS (A = xin1 full, K=448) ----
  mfma_gemm_k<<<gqkvs, blk, 0, stream>>>(xin1, D1, NN, D1, Wc1t, bc1, qb, kb, vb, skipb);
  init_k<<<initg, blk, 0, stream>>>(svec, agg);
  for (int ch = 0; ch < NCH; ++ch) {
    eabf_k<<<(CH * ND + 255) / 256, blk, 0, stream>>>(eattr, relt, tw, tb, ch * CH, eabf);
    mfma_gemm_k<<<gep, blk, 0, stream>>>(eabf, ND, CH, ND, We1t, nullptr, eprojc, eprojc, eprojc, eprojc);
    edge_pass_k<<<epg, blk, 0, stream>>>(qb, kb, vb, eprojc, ch * CH, CH, srcv, tgtv, svec, agg);
  }
  finish1_k<<<initg, blk, 0, stream>>>(agg, svec, skipb, qb);

  // ---- final linear: d_out = h1 @ linW + linb (small, stays f32) ----
  gemm_k<<<gf, blk, 0, stream>>>(qb, HC, NN, HC, linW, OUTD, linb, (float*)d_out, OUTD);
}